// Round 6
// baseline (1325.001 us; speedup 1.0000x reference)
//
#include <hip/hip_runtime.h>

// ---------------------------------------------------------------------------
// 3-layer GCN (DGL GraphConv, norm='both') on N=100k nodes, E=800k edges.
// Round 6: slice-major feature layout. y/hb/xb stored as 8 (or 4) slices of
// 16 bf16 cols, each slice [N][16] = 3.2 MB -> fits per-XCD L2. Gather blocks
// stage their 64 nodes' bucket records in LDS once and loop slices inside the
// kernel; all blocks co-resident => per-slice random reads are L2-hits.
// GEMM A-loads / C-stores are slice-major (fully coalesced).
// Per layer: y = bf16(hb @ W) ; hb' = bf16(relu(gather(y)*invi + b) * invo)
// ---------------------------------------------------------------------------

typedef short s16x8 __attribute__((ext_vector_type(8)));
typedef float f32x4 __attribute__((ext_vector_type(4)));

static constexpr int CAP = 16;   // bucket slots per node

__device__ __forceinline__ unsigned short f2bf(float f) {
    unsigned int u = __float_as_uint(f);
    u += 0x7FFFu + ((u >> 16) & 1u);   // round-to-nearest-even
    return (unsigned short)(u >> 16);
}
__device__ __forceinline__ float bf2f(unsigned short v) {
    return __uint_as_float((unsigned int)v << 16);
}

// ---- fused bucket fill + degree histograms (one pass over edges) ----
__global__ __launch_bounds__(256)
void fill_bucket(const int* __restrict__ src, const int* __restrict__ dst,
                 const float* __restrict__ w, int E,
                 int* __restrict__ dego, int* __restrict__ cursor,
                 float4* __restrict__ swb,
                 int* __restrict__ spill_cnt, int2* __restrict__ spill) {
    int e = blockIdx.x * blockDim.x + threadIdx.x;
    if (e >= E) return;
    int s = src[e];
    int d = dst[e];
    atomicAdd(&dego[s], 1);
    int pos = atomicAdd(&cursor[d], 1);
    if (pos < CAP) {
        swb[(size_t)d * CAP + pos] =
            make_float4(__int_as_float(s), w[e], w[E + e], w[2 * (size_t)E + e]);
    } else {
        int sp = atomicAdd(spill_cnt, 1);
        spill[sp] = make_int2(d, e);
    }
}

__global__ void invsqrt_kernel(const int* __restrict__ dego, const int* __restrict__ degi,
                               float* __restrict__ invo, float* __restrict__ invi, int N) {
    int i = blockIdx.x * blockDim.x + threadIdx.x;
    if (i < N) {
        int a = dego[i]; if (a < 1) a = 1;
        int b = degi[i]; if (b < 1) b = 1;
        invo[i] = 1.0f / sqrtf((float)a);
        invi[i] = 1.0f / sqrtf((float)b);
    }
}

// ---- pre-pack W[128][dact] (f32) into MFMA fragment order (bf16), pad to PC
__global__ void pack_w(const float* __restrict__ W, int dact, int PC,
                       unsigned short* __restrict__ Wp) {
    int idx = blockIdx.x * blockDim.x + threadIdx.x;
    if (idx >= 128 * PC) return;
    int k = idx / PC, col = idx % PC;
    float v = (col < dact) ? W[(size_t)k * dact + col] : 0.0f;
    int CT = PC / 16;
    int kk = k >> 5, kr = k & 31;
    int lane = ((kr >> 3) << 4) | (col & 15);
    int ct = col >> 4, j = kr & 7;
    Wp[(((size_t)(kk * CT) + ct) * 64 + lane) * 8 + j] = f2bf(v);
}

// ---- layer-0 input prescale: xb(slice-major) = bf16(x * invo[row]) ----
__global__ __launch_bounds__(256)
void prescale(const float* __restrict__ x, const float* __restrict__ invo,
              unsigned short* __restrict__ xb, int N) {
    int gid = blockIdx.x * blockDim.x + threadIdx.x;   // over N*32 float4s
    if (gid >= N * 32) return;
    int row = gid >> 5, c4 = gid & 31;
    float s = invo[row];
    float4 v = *(const float4*)&x[(size_t)gid * 4];
    ushort4 o;
    o.x = f2bf(v.x * s); o.y = f2bf(v.y * s);
    o.z = f2bf(v.z * s); o.w = f2bf(v.w * s);
    int slice = c4 >> 2, off = c4 & 3;
    *(ushort4*)&xb[((size_t)slice * N + row) * 16 + off * 4] = o;
}

// ---------------------------------------------------------------------------
// LDS-free MFMA GEMM, slice-major in/out:
//   y_s[ct][N][16](bf16) = bf16( h_s @ Wp ), h_s = 8 slices [N][16] bf16.
// Block = 4 waves = 64 rows; wave computes 16 rows x PC cols; K=128 in 4 steps.
// A fragment for lane: rows ar=row0+(lane&15), k = kk*32 + kgrp*8 + j
//   -> slice sa = kk*2 + (kgrp>>1), offset oa = (kgrp&1)*8  (16B load).
// C/D: col = ct*16 + (lane&15), row = (lane>>4)*4 + i.
// ---------------------------------------------------------------------------
template<int PC>
__global__ __launch_bounds__(256)
void gemm_direct(const unsigned short* __restrict__ h,
                 const unsigned short* __restrict__ Wp,
                 unsigned short* __restrict__ y, int N) {
    constexpr int CT = PC / 16;
    const int lane = threadIdx.x & 63;
    const int wid  = threadIdx.x >> 6;
    const int row0 = blockIdx.x * 64 + wid * 16;
    const int kgrp = lane >> 4;
    const int c    = lane & 15;

    int ar = row0 + c;
    if (ar > N - 1) ar = N - 1;          // clamp (partial last block)

    f32x4 acc[CT];
    #pragma unroll
    for (int ct = 0; ct < CT; ++ct) acc[ct] = {0.f, 0.f, 0.f, 0.f};

    #pragma unroll
    for (int kk = 0; kk < 4; ++kk) {
        const int sa = kk * 2 + (kgrp >> 1);
        const int oa = (kgrp & 1) * 8;
        s16x8 af = *(const s16x8*)&h[((size_t)sa * N + ar) * 16 + oa];
        #pragma unroll
        for (int ct = 0; ct < CT; ++ct) {
            s16x8 bf = *(const s16x8*)&Wp[((size_t)(kk * CT + ct) * 64 + lane) * 8];
            acc[ct] = __builtin_amdgcn_mfma_f32_16x16x32_bf16(af, bf, acc[ct], 0, 0, 0);
        }
    }

    #pragma unroll
    for (int ct = 0; ct < CT; ++ct) {
        #pragma unroll
        for (int i = 0; i < 4; ++i) {
            int row = row0 + kgrp * 4 + i;
            if (row < N) y[((size_t)ct * N + row) * 16 + c] = f2bf(acc[ct][i]);
        }
    }
}

// ---------------------------------------------------------------------------
// Slice-looped bucket gather + fused finalize.
// Block = 64 nodes x 4 threads. Records staged in LDS once; slices processed
// sequentially so the per-slice y working set (3.2 MB) stays L2-resident.
// WSEL picks weight component. Non-final: hb slice-major bf16. Final: f32
// pitch 47.
// ---------------------------------------------------------------------------
template<int PC, int WSEL, bool FINAL>
__global__ __launch_bounds__(256)
void gather_s(const unsigned short* __restrict__ ys, const float4* __restrict__ swb,
              const int* __restrict__ degi, const int* __restrict__ spill_cnt,
              const int2* __restrict__ spill, const int* __restrict__ src,
              const float* __restrict__ wl, const float* __restrict__ invi,
              const float* __restrict__ invo, const float* __restrict__ b,
              void* __restrict__ outp, int N) {
    constexpr int NSL = PC / 16;
    __shared__ float4 recs[64][CAP + 1];     // +1 pad: avoid bank aliasing

    const int n0 = blockIdx.x * 64;
    for (int idx = threadIdx.x; idx < 64 * CAP; idx += 256) {
        int nn = idx / CAP, pp = idx % CAP;
        if (n0 + nn < N) recs[nn][pp] = swb[(size_t)(n0 + nn) * CAP + pp];
    }
    __syncthreads();

    const int node = threadIdx.x >> 2;
    const int off  = threadIdx.x & 3;
    const int n = n0 + node;
    if (n >= N) return;

    const int dg  = degi[n];
    const int cnt = dg < CAP ? dg : CAP;
    const float inv = invi[n];
    const float io  = FINAL ? 0.f : invo[n];
    const int sc = (dg > CAP) ? *spill_cnt : 0;

    #pragma unroll 1
    for (int s = 0; s < NSL; ++s) {
        const unsigned short* ysl = ys + (size_t)s * N * 16;
        float a0 = 0.f, a1 = 0.f, a2 = 0.f, a3 = 0.f;
        int p = 0;
        for (; p + 2 <= cnt; p += 2) {
            float4 m0 = recs[node][p];
            float4 m1 = recs[node][p + 1];
            int s0 = __float_as_int(m0.x);
            int s1 = __float_as_int(m1.x);
            float w0 = (WSEL == 0) ? m0.y : (WSEL == 1) ? m0.z : m0.w;
            float w1 = (WSEL == 0) ? m1.y : (WSEL == 1) ? m1.z : m1.w;
            ushort4 v0 = *(const ushort4*)&ysl[(size_t)s0 * 16 + off * 4];
            ushort4 v1 = *(const ushort4*)&ysl[(size_t)s1 * 16 + off * 4];
            a0 = fmaf(bf2f(v0.x), w0, a0);
            a1 = fmaf(bf2f(v0.y), w0, a1);
            a2 = fmaf(bf2f(v0.z), w0, a2);
            a3 = fmaf(bf2f(v0.w), w0, a3);
            a0 = fmaf(bf2f(v1.x), w1, a0);
            a1 = fmaf(bf2f(v1.y), w1, a1);
            a2 = fmaf(bf2f(v1.z), w1, a2);
            a3 = fmaf(bf2f(v1.w), w1, a3);
        }
        if (p < cnt) {
            float4 m0 = recs[node][p];
            int s0 = __float_as_int(m0.x);
            float w0 = (WSEL == 0) ? m0.y : (WSEL == 1) ? m0.z : m0.w;
            ushort4 v0 = *(const ushort4*)&ysl[(size_t)s0 * 16 + off * 4];
            a0 = fmaf(bf2f(v0.x), w0, a0);
            a1 = fmaf(bf2f(v0.y), w0, a1);
            a2 = fmaf(bf2f(v0.z), w0, a2);
            a3 = fmaf(bf2f(v0.w), w0, a3);
        }
        for (int i = 0; i < sc; ++i) {       // rare exact-overflow path
            int2 sp = spill[i];
            if (sp.x == n) {
                int e = sp.y;
                int s0 = src[e];
                float w0 = wl[e];
                ushort4 v0 = *(const ushort4*)&ysl[(size_t)s0 * 16 + off * 4];
                a0 = fmaf(bf2f(v0.x), w0, a0);
                a1 = fmaf(bf2f(v0.y), w0, a1);
                a2 = fmaf(bf2f(v0.z), w0, a2);
                a3 = fmaf(bf2f(v0.w), w0, a3);
            }
        }

        if (FINAL) {
            float* out = (float*)outp;
            const int c = s * 16 + off * 4;
            float aa[4] = {a0, a1, a2, a3};
            #pragma unroll
            for (int j = 0; j < 4; ++j) {
                if (c + j < 47) out[(size_t)n * 47 + c + j] = fmaf(aa[j], inv, b[c + j]);
            }
        } else {
            unsigned short* out = (unsigned short*)outp;
            float4 bb = *(const float4*)&b[s * 16 + off * 4];
            float4 v;
            v.x = fmaxf(fmaf(a0, inv, bb.x), 0.f) * io;
            v.y = fmaxf(fmaf(a1, inv, bb.y), 0.f) * io;
            v.z = fmaxf(fmaf(a2, inv, bb.z), 0.f) * io;
            v.w = fmaxf(fmaf(a3, inv, bb.w), 0.f) * io;
            ushort4 o;
            o.x = f2bf(v.x); o.y = f2bf(v.y); o.z = f2bf(v.z); o.w = f2bf(v.w);
            *(ushort4*)&out[((size_t)s * N + n) * 16 + off * 4] = o;
        }
    }
}

extern "C" void kernel_launch(void* const* d_in, const int* in_sizes, int n_in,
                              void* d_out, int out_size, void* d_ws, size_t ws_size,
                              hipStream_t stream) {
    const float* x   = (const float*)d_in[0];
    const int*   src = (const int*)d_in[1];
    const int*   dst = (const int*)d_in[2];
    const float* w   = (const float*)d_in[3];
    const float* W0  = (const float*)d_in[4];
    const float* b0  = (const float*)d_in[5];
    const float* W1  = (const float*)d_in[6];
    const float* b1  = (const float*)d_in[7];
    const float* W2  = (const float*)d_in[8];
    const float* b2  = (const float*)d_in[9];

    const int N = in_sizes[0] / 128;
    const int E = in_sizes[1];

    char* p = (char*)d_ws;
    unsigned short* xb = (unsigned short*)p; p += (size_t)N * 128 * sizeof(unsigned short);
    unsigned short* hb = (unsigned short*)p; p += (size_t)N * 128 * sizeof(unsigned short);
    unsigned short* y  = (unsigned short*)p; p += (size_t)N * 128 * sizeof(unsigned short);
    float4* swb    = (float4*)p; p += (size_t)N * CAP * sizeof(float4);
    int2*   spill  = (int2*)p;   p += (size_t)E * sizeof(int2);
    unsigned short* Wp = (unsigned short*)p; p += (size_t)(16384 * 2 + 8192) * sizeof(unsigned short);
    int*   dego    = (int*)p;    p += (size_t)N * sizeof(int);
    int*   cursor  = (int*)p;    p += (size_t)N * sizeof(int);   // becomes degi
    int*   spill_cnt = (int*)p;  p += 4 * sizeof(int);
    float* invo    = (float*)p;  p += (size_t)N * sizeof(float);
    float* invi    = (float*)p;  p += (size_t)N * sizeof(float);

    unsigned short* Wp0 = Wp;
    unsigned short* Wp1 = Wp + 16384;
    unsigned short* Wp2 = Wp + 32768;

    // ---- weight packs ----
    pack_w<<<(128 * 128 + 255) / 256, 256, 0, stream>>>(W0, 128, 128, Wp0);
    pack_w<<<(128 * 128 + 255) / 256, 256, 0, stream>>>(W1, 128, 128, Wp1);
    pack_w<<<(128 * 64 + 255) / 256, 256, 0, stream>>>(W2, 47, 64, Wp2);

    // ---- fused bucket build (degrees + records + spill) ----
    hipMemsetAsync(dego, 0, (2 * (size_t)N + 4) * sizeof(int), stream);
    fill_bucket<<<(E + 255) / 256, 256, 0, stream>>>(
        src, dst, w, E, dego, cursor, swb, spill_cnt, spill);
    invsqrt_kernel<<<(N + 255) / 256, 256, 0, stream>>>(dego, cursor, invo, invi, N);

    // ---- layer-0 input prescale (slice-major bf16) ----
    prescale<<<(N * 32 + 255) / 256, 256, 0, stream>>>(x, invo, xb, N);

    const int gemm_blocks   = (N + 63) / 64;
    const int gather_blocks = (N + 63) / 64;

    // ---- layer 0: xb -> hb ----
    gemm_direct<128><<<gemm_blocks, 256, 0, stream>>>(xb, Wp0, y, N);
    gather_s<128, 0, false><<<gather_blocks, 256, 0, stream>>>(
        y, swb, cursor, spill_cnt, spill, src, w, invi, invo, b0, hb, N);

    // ---- layer 1: hb -> hb ----
    gemm_direct<128><<<gemm_blocks, 256, 0, stream>>>(hb, Wp1, y, N);
    gather_s<128, 1, false><<<gather_blocks, 256, 0, stream>>>(
        y, swb, cursor, spill_cnt, spill, src, w + E, invi, invo, b1, hb, N);

    // ---- layer 2: hb -> d_out ----
    gemm_direct<64><<<gemm_blocks, 256, 0, stream>>>(hb, Wp2, y, N);
    gather_s<64, 2, true><<<gather_blocks, 256, 0, stream>>>(
        y, swb, cursor, spill_cnt, spill, src, w + 2 * (size_t)E, invi, invo, b2, d_out, N);
}

// Round 7
// 391.496 us; speedup vs baseline: 3.3845x; 3.3845x over previous
//
#include <hip/hip_runtime.h>

// ---------------------------------------------------------------------------
// 3-layer GCN (DGL GraphConv, norm='both') on N=100k nodes, E=800k edges.
// Round 7: revert slice-major (round-6 regression). One-pass bucket build
// (degrees + float4 records + spill) -> scan of min(deg,CAP) -> compact into
// per-layer CONTIGUOUS float2 CSR meta (streamed gather metadata). Gather =
// round-4 CSR style, 4-way unrolled (4 independent y-row fetches in flight).
// GEMM = LDS-free MFMA (row-major bf16 h, pre-packed W fragments).
// Per layer: y = bf16(hb @ W) ; hb' = bf16(relu(gather(y)*invi + b) * invo)
// ---------------------------------------------------------------------------

typedef short s16x8 __attribute__((ext_vector_type(8)));
typedef float f32x4 __attribute__((ext_vector_type(4)));

static constexpr int CAP = 16;   // bucket slots per node

__device__ __forceinline__ unsigned short f2bf(float f) {
    unsigned int u = __float_as_uint(f);
    u += 0x7FFFu + ((u >> 16) & 1u);   // round-to-nearest-even
    return (unsigned short)(u >> 16);
}
__device__ __forceinline__ float bf2f(unsigned short v) {
    return __uint_as_float((unsigned int)v << 16);
}

// ---- fused bucket fill + degree histograms (one pass over edges) ----
__global__ __launch_bounds__(256)
void fill_bucket(const int* __restrict__ src, const int* __restrict__ dst,
                 const float* __restrict__ w, int E,
                 int* __restrict__ dego, int* __restrict__ cursor,
                 float4* __restrict__ swb,
                 int* __restrict__ spill_cnt, int2* __restrict__ spill) {
    int e = blockIdx.x * blockDim.x + threadIdx.x;
    if (e >= E) return;
    int s = src[e];
    int d = dst[e];
    atomicAdd(&dego[s], 1);
    int pos = atomicAdd(&cursor[d], 1);
    if (pos < CAP) {
        swb[(size_t)d * CAP + pos] =
            make_float4(__int_as_float(s), w[e], w[E + e], w[2 * (size_t)E + e]);
    } else {
        int sp = atomicAdd(spill_cnt, 1);
        spill[sp] = make_int2(d, e);
    }
}

// norms + clamped bucket count
__global__ void invsqrt_cnt(const int* __restrict__ dego, const int* __restrict__ degi,
                            float* __restrict__ invo, float* __restrict__ invi,
                            int* __restrict__ cnt, int N) {
    int i = blockIdx.x * blockDim.x + threadIdx.x;
    if (i < N) {
        int a = dego[i]; if (a < 1) a = 1;
        int b = degi[i]; if (b < 1) b = 1;
        invo[i] = 1.0f / sqrtf((float)a);
        invi[i] = 1.0f / sqrtf((float)b);
        int c = degi[i];
        cnt[i] = c < CAP ? c : CAP;
    }
}

// ---- prefix sum of cnt -> ofs (exclusive), 1024 elems per block ----
__global__ __launch_bounds__(256)
void scan_block(const int* __restrict__ deg, int* __restrict__ ofs,
                int* __restrict__ bsum, int N) {
    __shared__ int sh[256];
    const int base = blockIdx.x * 1024;
    const int t = threadIdx.x;
    int v[4]; int s = 0;
    #pragma unroll
    for (int i = 0; i < 4; ++i) {
        int idx = base + t * 4 + i;
        v[i] = (idx < N) ? deg[idx] : 0;
        s += v[i];
    }
    sh[t] = s;
    __syncthreads();
    #pragma unroll
    for (int off = 1; off < 256; off <<= 1) {
        int x = (t >= off) ? sh[t - off] : 0;
        __syncthreads();
        sh[t] += x;
        __syncthreads();
    }
    int excl = (t == 0) ? 0 : sh[t - 1];
    #pragma unroll
    for (int i = 0; i < 4; ++i) {
        int idx = base + t * 4 + i;
        if (idx < N) ofs[idx] = excl;
        excl += v[i];
    }
    if (t == 255) bsum[blockIdx.x] = sh[255];
}

__global__ __launch_bounds__(256)
void scan_top(int* __restrict__ bsum, int nb) {
    __shared__ int sh[256];
    const int t = threadIdx.x;
    sh[t] = (t < nb) ? bsum[t] : 0;
    __syncthreads();
    #pragma unroll
    for (int off = 1; off < 256; off <<= 1) {
        int x = (t >= off) ? sh[t - off] : 0;
        __syncthreads();
        sh[t] += x;
        __syncthreads();
    }
    int excl = (t == 0) ? 0 : sh[t - 1];
    if (t < nb) bsum[t] = excl;
}

__global__ void add_offsets(int* __restrict__ ofs, const int* __restrict__ bsum, int N) {
    int i = blockIdx.x * blockDim.x + threadIdx.x;
    if (i < N) ofs[i] += bsum[i >> 10];
}

// ---- compact bucket float4 -> per-layer contiguous float2 CSR meta ----
__global__ __launch_bounds__(256)
void compact(const float4* __restrict__ swb, const int* __restrict__ cnt,
             const int* __restrict__ ofs,
             float2* __restrict__ sw0, float2* __restrict__ sw1,
             float2* __restrict__ sw2, int N) {
    int idx = blockIdx.x * blockDim.x + threadIdx.x;
    if (idx >= N * CAP) return;
    int n = idx >> 4;            // CAP = 16
    int p = idx & 15;
    if (p < cnt[n]) {
        float4 r = swb[idx];
        int o = ofs[n] + p;
        sw0[o] = make_float2(r.x, r.y);
        sw1[o] = make_float2(r.x, r.z);
        sw2[o] = make_float2(r.x, r.w);
    }
}

// ---- pre-pack W[128][dact] (f32) into MFMA fragment order (bf16), pad to PC
// Fragment mapping (same for A and B, cancels HW k-order):
//   k = kk*32 + (lane>>4)*8 + j ; col = ct*16 + (lane&15)
__global__ void pack_w(const float* __restrict__ W, int dact, int PC,
                       unsigned short* __restrict__ Wp) {
    int idx = blockIdx.x * blockDim.x + threadIdx.x;
    if (idx >= 128 * PC) return;
    int k = idx / PC, col = idx % PC;
    float v = (col < dact) ? W[(size_t)k * dact + col] : 0.0f;
    int CT = PC / 16;
    int kk = k >> 5, kr = k & 31;
    int lane = ((kr >> 3) << 4) | (col & 15);
    int ct = col >> 4, j = kr & 7;
    Wp[(((size_t)(kk * CT) + ct) * 64 + lane) * 8 + j] = f2bf(v);
}

// ---- layer-0 input prescale: xb = bf16(x * invo[row]), row-major ----
__global__ __launch_bounds__(256)
void prescale(const float* __restrict__ x, const float* __restrict__ invo,
              unsigned short* __restrict__ xb, int N) {
    int gid = blockIdx.x * blockDim.x + threadIdx.x;   // over N*32 float4s
    if (gid >= N * 32) return;
    int row = gid >> 5;
    float s = invo[row];
    float4 v = *(const float4*)&x[(size_t)gid * 4];
    ushort4 o;
    o.x = f2bf(v.x * s); o.y = f2bf(v.y * s);
    o.z = f2bf(v.z * s); o.w = f2bf(v.w * s);
    *(ushort4*)&xb[(size_t)gid * 4] = o;
}

// ---------------------------------------------------------------------------
// LDS-free MFMA GEMM: y[N][PC](bf16) = bf16( h[N][128](bf16) @ Wp )
// Block = 4 waves = 64 rows; wave computes 16 rows x PC cols; K=128 in 4 steps.
// C/D layout: col = ct*16 + (lane&15), row = (lane>>4)*4 + i.
// ---------------------------------------------------------------------------
template<int PC>
__global__ __launch_bounds__(256)
void gemm_direct(const unsigned short* __restrict__ h,
                 const unsigned short* __restrict__ Wp,
                 unsigned short* __restrict__ y, int N) {
    constexpr int CT = PC / 16;
    const int lane = threadIdx.x & 63;
    const int wid  = threadIdx.x >> 6;
    const int row0 = blockIdx.x * 64 + wid * 16;
    const int kgrp = lane >> 4;
    const int c    = lane & 15;

    int ar = row0 + c;
    if (ar > N - 1) ar = N - 1;          // clamp (partial last block)
    const unsigned short* hrow = &h[(size_t)ar * 128 + kgrp * 8];

    f32x4 acc[CT];
    #pragma unroll
    for (int ct = 0; ct < CT; ++ct) acc[ct] = {0.f, 0.f, 0.f, 0.f};

    #pragma unroll
    for (int kk = 0; kk < 4; ++kk) {
        s16x8 af = *(const s16x8*)&hrow[kk * 32];
        #pragma unroll
        for (int ct = 0; ct < CT; ++ct) {
            s16x8 bf = *(const s16x8*)&Wp[((size_t)(kk * CT + ct) * 64 + lane) * 8];
            acc[ct] = __builtin_amdgcn_mfma_f32_16x16x32_bf16(af, bf, acc[ct], 0, 0, 0);
        }
    }

    #pragma unroll
    for (int ct = 0; ct < CT; ++ct) {
        #pragma unroll
        for (int i = 0; i < 4; ++i) {
            int row = row0 + kgrp * 4 + i;
            if (row < N) y[(size_t)row * PC + ct * 16 + c] = f2bf(acc[ct][i]);
        }
    }
}

// ---------------------------------------------------------------------------
// CSR gather + fused finalize, contiguous float2 meta, 4-way unroll.
// D = feature pitch of y. TPN = D/4 threads per node (ushort4 each).
// Non-final: out = bf16( relu(acc*invi + b) * invo ), pitch 128 bf16.
// Final:     out = acc*invi + b, f32, pitch 47, cols < 47 only.
// ---------------------------------------------------------------------------
template<int D, bool FINAL>
__global__ __launch_bounds__(256)
void gather_c(const unsigned short* __restrict__ yb, const int* __restrict__ ofs,
              const int* __restrict__ degi, const float2* __restrict__ sw,
              const int* __restrict__ spill_cnt, const int2* __restrict__ spill,
              const int* __restrict__ src, const float* __restrict__ wl,
              const float* __restrict__ invi, const float* __restrict__ invo,
              const float* __restrict__ b, void* __restrict__ outp, int N) {
    constexpr int TPN = D / 4;          // threads per node
    constexpr int NPB = 256 / TPN;      // nodes per block
    const int n    = blockIdx.x * NPB + threadIdx.x / TPN;
    const int lane = threadIdx.x % TPN;
    if (n >= N) return;

    const ushort4* yv = (const ushort4*)yb;
    const int dg  = degi[n];
    const int cnt = dg < CAP ? dg : CAP;
    const int p0  = ofs[n];

    float a0 = 0.f, a1 = 0.f, a2 = 0.f, a3 = 0.f;
    int p = 0;
    for (; p + 4 <= cnt; p += 4) {
        float2 m0 = sw[p0 + p];
        float2 m1 = sw[p0 + p + 1];
        float2 m2 = sw[p0 + p + 2];
        float2 m3 = sw[p0 + p + 3];
        ushort4 v0 = yv[(size_t)__float_as_int(m0.x) * TPN + lane];
        ushort4 v1 = yv[(size_t)__float_as_int(m1.x) * TPN + lane];
        ushort4 v2 = yv[(size_t)__float_as_int(m2.x) * TPN + lane];
        ushort4 v3 = yv[(size_t)__float_as_int(m3.x) * TPN + lane];
        a0 = fmaf(bf2f(v0.x), m0.y, a0);
        a1 = fmaf(bf2f(v0.y), m0.y, a1);
        a2 = fmaf(bf2f(v0.z), m0.y, a2);
        a3 = fmaf(bf2f(v0.w), m0.y, a3);
        a0 = fmaf(bf2f(v1.x), m1.y, a0);
        a1 = fmaf(bf2f(v1.y), m1.y, a1);
        a2 = fmaf(bf2f(v1.z), m1.y, a2);
        a3 = fmaf(bf2f(v1.w), m1.y, a3);
        a0 = fmaf(bf2f(v2.x), m2.y, a0);
        a1 = fmaf(bf2f(v2.y), m2.y, a1);
        a2 = fmaf(bf2f(v2.z), m2.y, a2);
        a3 = fmaf(bf2f(v2.w), m2.y, a3);
        a0 = fmaf(bf2f(v3.x), m3.y, a0);
        a1 = fmaf(bf2f(v3.y), m3.y, a1);
        a2 = fmaf(bf2f(v3.z), m3.y, a2);
        a3 = fmaf(bf2f(v3.w), m3.y, a3);
    }
    for (; p < cnt; ++p) {
        float2 m0 = sw[p0 + p];
        ushort4 v0 = yv[(size_t)__float_as_int(m0.x) * TPN + lane];
        a0 = fmaf(bf2f(v0.x), m0.y, a0);
        a1 = fmaf(bf2f(v0.y), m0.y, a1);
        a2 = fmaf(bf2f(v0.z), m0.y, a2);
        a3 = fmaf(bf2f(v0.w), m0.y, a3);
    }
    if (dg > CAP) {                      // rare exact-overflow path
        int sc = *spill_cnt;
        for (int i = 0; i < sc; ++i) {
            int2 sp = spill[i];
            if (sp.x == n) {
                int e = sp.y;
                int s0 = src[e];
                float w0 = wl[e];
                ushort4 v0 = yv[(size_t)s0 * TPN + lane];
                a0 = fmaf(bf2f(v0.x), w0, a0);
                a1 = fmaf(bf2f(v0.y), w0, a1);
                a2 = fmaf(bf2f(v0.z), w0, a2);
                a3 = fmaf(bf2f(v0.w), w0, a3);
            }
        }
    }

    const float inv = invi[n];
    if (FINAL) {
        float* out = (float*)outp;
        const int c = lane * 4;
        float aa[4] = {a0, a1, a2, a3};
        #pragma unroll
        for (int j = 0; j < 4; ++j) {
            if (c + j < 47) out[(size_t)n * 47 + c + j] = fmaf(aa[j], inv, b[c + j]);
        }
    } else {
        unsigned short* out = (unsigned short*)outp;
        const float io = invo[n];
        float4 bb = *(const float4*)&b[lane * 4];
        float4 v;
        v.x = fmaxf(fmaf(a0, inv, bb.x), 0.f) * io;
        v.y = fmaxf(fmaf(a1, inv, bb.y), 0.f) * io;
        v.z = fmaxf(fmaf(a2, inv, bb.z), 0.f) * io;
        v.w = fmaxf(fmaf(a3, inv, bb.w), 0.f) * io;
        ushort4 o;
        o.x = f2bf(v.x); o.y = f2bf(v.y); o.z = f2bf(v.z); o.w = f2bf(v.w);
        *(ushort4*)&out[(size_t)n * D + lane * 4] = o;
    }
}

extern "C" void kernel_launch(void* const* d_in, const int* in_sizes, int n_in,
                              void* d_out, int out_size, void* d_ws, size_t ws_size,
                              hipStream_t stream) {
    const float* x   = (const float*)d_in[0];
    const int*   src = (const int*)d_in[1];
    const int*   dst = (const int*)d_in[2];
    const float* w   = (const float*)d_in[3];
    const float* W0  = (const float*)d_in[4];
    const float* b0  = (const float*)d_in[5];
    const float* W1  = (const float*)d_in[6];
    const float* b1  = (const float*)d_in[7];
    const float* W2  = (const float*)d_in[8];
    const float* b2  = (const float*)d_in[9];

    const int N = in_sizes[0] / 128;
    const int E = in_sizes[1];

    char* p = (char*)d_ws;
    unsigned short* xh = (unsigned short*)p; p += (size_t)N * 128 * sizeof(unsigned short); // x_bf16 then hb (aliased)
    unsigned short* y  = (unsigned short*)p; p += (size_t)N * 128 * sizeof(unsigned short);
    float4* swb    = (float4*)p; p += (size_t)N * CAP * sizeof(float4);
    float2* sw0    = (float2*)p; p += (size_t)E * sizeof(float2);
    float2* sw1    = (float2*)p; p += (size_t)E * sizeof(float2);
    float2* sw2    = (float2*)p; p += (size_t)E * sizeof(float2);
    int2*   spill  = (int2*)p;   p += (size_t)E * sizeof(int2);
    unsigned short* Wp = (unsigned short*)p; p += (size_t)(16384 * 2 + 8192) * sizeof(unsigned short);
    int*   dego    = (int*)p;    p += (size_t)N * sizeof(int);
    int*   cursor  = (int*)p;    p += (size_t)N * sizeof(int);   // becomes degi
    int*   spill_cnt = (int*)p;  p += 4 * sizeof(int);
    int*   cnt     = (int*)p;    p += (size_t)N * sizeof(int);
    int*   ofs     = (int*)p;    p += (size_t)N * sizeof(int);
    float* invo    = (float*)p;  p += (size_t)N * sizeof(float);
    float* invi    = (float*)p;  p += (size_t)N * sizeof(float);
    int*   bsum    = (int*)p;    p += 256 * sizeof(int);

    unsigned short* Wp0 = Wp;
    unsigned short* Wp1 = Wp + 16384;
    unsigned short* Wp2 = Wp + 32768;

    // ---- weight packs ----
    pack_w<<<(128 * 128 + 255) / 256, 256, 0, stream>>>(W0, 128, 128, Wp0);
    pack_w<<<(128 * 128 + 255) / 256, 256, 0, stream>>>(W1, 128, 128, Wp1);
    pack_w<<<(128 * 64 + 255) / 256, 256, 0, stream>>>(W2, 47, 64, Wp2);

    // ---- one-pass bucket build (degrees + records + spill) ----
    hipMemsetAsync(dego, 0, (2 * (size_t)N + 4) * sizeof(int), stream);
    fill_bucket<<<(E + 255) / 256, 256, 0, stream>>>(
        src, dst, w, E, dego, cursor, swb, spill_cnt, spill);
    invsqrt_cnt<<<(N + 255) / 256, 256, 0, stream>>>(dego, cursor, invo, invi, cnt, N);

    // ---- offsets (scan of cnt) + compact to per-layer CSR meta ----
    const int nb = (N + 1023) / 1024;
    scan_block<<<nb, 256, 0, stream>>>(cnt, ofs, bsum, N);
    scan_top<<<1, 256, 0, stream>>>(bsum, nb);
    add_offsets<<<(N + 255) / 256, 256, 0, stream>>>(ofs, bsum, N);
    compact<<<(N * CAP + 255) / 256, 256, 0, stream>>>(swb, cnt, ofs, sw0, sw1, sw2, N);

    // ---- layer-0 input prescale ----
    prescale<<<(N * 32 + 255) / 256, 256, 0, stream>>>(x, invo, xh, N);

    const int gemm_blocks = (N + 63) / 64;

    // ---- layer 0: xh -> xh (via y) ----
    gemm_direct<128><<<gemm_blocks, 256, 0, stream>>>(xh, Wp0, y, N);
    gather_c<128, false><<<(N + 7) / 8, 256, 0, stream>>>(
        y, ofs, cursor, sw0, spill_cnt, spill, src, w, invi, invo, b0, xh, N);

    // ---- layer 1: xh -> xh ----
    gemm_direct<128><<<gemm_blocks, 256, 0, stream>>>(xh, Wp1, y, N);
    gather_c<128, false><<<(N + 7) / 8, 256, 0, stream>>>(
        y, ofs, cursor, sw1, spill_cnt, spill, src, w + E, invi, invo, b1, xh, N);

    // ---- layer 2: xh -> d_out ----
    gemm_direct<64><<<gemm_blocks, 256, 0, stream>>>(xh, Wp2, y, N);
    gather_c<64, true><<<(N + 15) / 16, 256, 0, stream>>>(
        y, ofs, cursor, sw2, spill_cnt, spill, src, w + 2 * (size_t)E, invi, invo, b2, d_out, N);
}

// Round 8
// 294.582 us; speedup vs baseline: 4.4979x; 1.3290x over previous
//
#include <hip/hip_runtime.h>

// ---------------------------------------------------------------------------
// 3-layer GCN (DGL GraphConv, norm='both') on N=100k nodes, E=800k edges.
// Round 8: wave-per-node gather with edge-parallel groups (EPG) + shfl_xor
// combine; bucket records read directly (scan/compact removed); CAP=24 so the
// exact-spill path is empty in expectation.
// Per layer: y = bf16(hb @ W) ; hb' = bf16(relu(gather(y)*invi + b) * invo)
// ---------------------------------------------------------------------------

typedef short s16x8 __attribute__((ext_vector_type(8)));
typedef float f32x4 __attribute__((ext_vector_type(4)));

static constexpr int CAP = 24;   // bucket slots per node (P(deg>24)~1e-6)

__device__ __forceinline__ unsigned short f2bf(float f) {
    unsigned int u = __float_as_uint(f);
    u += 0x7FFFu + ((u >> 16) & 1u);   // round-to-nearest-even
    return (unsigned short)(u >> 16);
}
__device__ __forceinline__ float bf2f(unsigned short v) {
    return __uint_as_float((unsigned int)v << 16);
}

// ---- fused bucket fill + degree histograms (one pass over edges) ----
__global__ __launch_bounds__(256)
void fill_bucket(const int* __restrict__ src, const int* __restrict__ dst,
                 const float* __restrict__ w, int E,
                 int* __restrict__ dego, int* __restrict__ cursor,
                 float4* __restrict__ swb,
                 int* __restrict__ spill_cnt, int2* __restrict__ spill) {
    int e = blockIdx.x * blockDim.x + threadIdx.x;
    if (e >= E) return;
    int s = src[e];
    int d = dst[e];
    atomicAdd(&dego[s], 1);
    int pos = atomicAdd(&cursor[d], 1);
    if (pos < CAP) {
        swb[(size_t)d * CAP + pos] =
            make_float4(__int_as_float(s), w[e], w[E + e], w[2 * (size_t)E + e]);
    } else {
        int sp = atomicAdd(spill_cnt, 1);
        spill[sp] = make_int2(d, e);
    }
}

__global__ void invsqrt_kernel(const int* __restrict__ dego, const int* __restrict__ degi,
                               float* __restrict__ invo, float* __restrict__ invi, int N) {
    int i = blockIdx.x * blockDim.x + threadIdx.x;
    if (i < N) {
        int a = dego[i]; if (a < 1) a = 1;
        int b = degi[i]; if (b < 1) b = 1;
        invo[i] = 1.0f / sqrtf((float)a);
        invi[i] = 1.0f / sqrtf((float)b);
    }
}

// ---- pre-pack W[128][dact] (f32) into MFMA fragment order (bf16), pad to PC
// Fragment mapping (same for A and B, cancels HW k-order):
//   k = kk*32 + (lane>>4)*8 + j ; col = ct*16 + (lane&15)
__global__ void pack_w(const float* __restrict__ W, int dact, int PC,
                       unsigned short* __restrict__ Wp) {
    int idx = blockIdx.x * blockDim.x + threadIdx.x;
    if (idx >= 128 * PC) return;
    int k = idx / PC, col = idx % PC;
    float v = (col < dact) ? W[(size_t)k * dact + col] : 0.0f;
    int CT = PC / 16;
    int kk = k >> 5, kr = k & 31;
    int lane = ((kr >> 3) << 4) | (col & 15);
    int ct = col >> 4, j = kr & 7;
    Wp[(((size_t)(kk * CT) + ct) * 64 + lane) * 8 + j] = f2bf(v);
}

// ---- layer-0 input prescale: xb = bf16(x * invo[row]), row-major ----
__global__ __launch_bounds__(256)
void prescale(const float* __restrict__ x, const float* __restrict__ invo,
              unsigned short* __restrict__ xb, int N) {
    int gid = blockIdx.x * blockDim.x + threadIdx.x;   // over N*32 float4s
    if (gid >= N * 32) return;
    int row = gid >> 5;
    float s = invo[row];
    float4 v = *(const float4*)&x[(size_t)gid * 4];
    ushort4 o;
    o.x = f2bf(v.x * s); o.y = f2bf(v.y * s);
    o.z = f2bf(v.z * s); o.w = f2bf(v.w * s);
    *(ushort4*)&xb[(size_t)gid * 4] = o;
}

// ---------------------------------------------------------------------------
// LDS-free MFMA GEMM: y[N][PC](bf16) = bf16( h[N][128](bf16) @ Wp )
// Block = 4 waves = 64 rows; wave computes 16 rows x PC cols; K=128 in 4 steps.
// C/D layout: col = ct*16 + (lane&15), row = (lane>>4)*4 + i.
// ---------------------------------------------------------------------------
template<int PC>
__global__ __launch_bounds__(256)
void gemm_direct(const unsigned short* __restrict__ h,
                 const unsigned short* __restrict__ Wp,
                 unsigned short* __restrict__ y, int N) {
    constexpr int CT = PC / 16;
    const int lane = threadIdx.x & 63;
    const int wid  = threadIdx.x >> 6;
    const int row0 = blockIdx.x * 64 + wid * 16;
    const int kgrp = lane >> 4;
    const int c    = lane & 15;

    int ar = row0 + c;
    if (ar > N - 1) ar = N - 1;          // clamp (partial last block)
    const unsigned short* hrow = &h[(size_t)ar * 128 + kgrp * 8];

    f32x4 acc[CT];
    #pragma unroll
    for (int ct = 0; ct < CT; ++ct) acc[ct] = {0.f, 0.f, 0.f, 0.f};

    #pragma unroll
    for (int kk = 0; kk < 4; ++kk) {
        s16x8 af = *(const s16x8*)&hrow[kk * 32];
        #pragma unroll
        for (int ct = 0; ct < CT; ++ct) {
            s16x8 bf = *(const s16x8*)&Wp[((size_t)(kk * CT + ct) * 64 + lane) * 8];
            acc[ct] = __builtin_amdgcn_mfma_f32_16x16x32_bf16(af, bf, acc[ct], 0, 0, 0);
        }
    }

    #pragma unroll
    for (int ct = 0; ct < CT; ++ct) {
        #pragma unroll
        for (int i = 0; i < 4; ++i) {
            int row = row0 + kgrp * 4 + i;
            if (row < N) y[(size_t)row * PC + ct * 16 + c] = f2bf(acc[ct][i]);
        }
    }
}

// ---------------------------------------------------------------------------
// Wave-per-node gather + fused finalize.
// PC = feature pitch of y. TPN = PC/4 lanes cover one row (ushort4 each);
// EPG = 64/TPN edge-parallel groups take interleaved edges; cross-group
// combine via __shfl_xor (no LDS). WSEL picks the weight component.
// Non-final: out = bf16( relu(acc*invi + b) * invo ), pitch 128 bf16.
// Final:     out = acc*invi + b, f32, pitch 47, cols < 47 only.
// ---------------------------------------------------------------------------
template<int PC, int WSEL, bool FINAL>
__global__ __launch_bounds__(256)
void gather_w(const unsigned short* __restrict__ yb, const float4* __restrict__ swb,
              const int* __restrict__ degi, const int* __restrict__ spill_cnt,
              const int2* __restrict__ spill, const int* __restrict__ src,
              const float* __restrict__ wl, const float* __restrict__ invi,
              const float* __restrict__ invo, const float* __restrict__ b,
              void* __restrict__ outp, int N) {
    constexpr int TPN = PC / 4;        // lanes per row (32 or 16)
    constexpr int EPG = 64 / TPN;      // edge groups per node (2 or 4)
    const int n = blockIdx.x * 4 + (threadIdx.x >> 6);
    if (n >= N) return;
    const int t    = threadIdx.x & 63;
    const int lane = t & (TPN - 1);
    const int g    = t / TPN;

    const ushort4* yv = (const ushort4*)yb;
    const float4* rec = swb + (size_t)n * CAP;
    const int dg  = degi[n];
    const int cnt = dg < CAP ? dg : CAP;

    float a0 = 0.f, a1 = 0.f, a2 = 0.f, a3 = 0.f;
    int p = g;
    for (; p + EPG < cnt; p += 2 * EPG) {
        float4 m0 = rec[p];
        float4 m1 = rec[p + EPG];
        float w0 = (WSEL == 0) ? m0.y : (WSEL == 1) ? m0.z : m0.w;
        float w1 = (WSEL == 0) ? m1.y : (WSEL == 1) ? m1.z : m1.w;
        ushort4 v0 = yv[(size_t)__float_as_int(m0.x) * TPN + lane];
        ushort4 v1 = yv[(size_t)__float_as_int(m1.x) * TPN + lane];
        a0 = fmaf(bf2f(v0.x), w0, a0);
        a1 = fmaf(bf2f(v0.y), w0, a1);
        a2 = fmaf(bf2f(v0.z), w0, a2);
        a3 = fmaf(bf2f(v0.w), w0, a3);
        a0 = fmaf(bf2f(v1.x), w1, a0);
        a1 = fmaf(bf2f(v1.y), w1, a1);
        a2 = fmaf(bf2f(v1.z), w1, a2);
        a3 = fmaf(bf2f(v1.w), w1, a3);
    }
    if (p < cnt) {
        float4 m0 = rec[p];
        float w0 = (WSEL == 0) ? m0.y : (WSEL == 1) ? m0.z : m0.w;
        ushort4 v0 = yv[(size_t)__float_as_int(m0.x) * TPN + lane];
        a0 = fmaf(bf2f(v0.x), w0, a0);
        a1 = fmaf(bf2f(v0.y), w0, a1);
        a2 = fmaf(bf2f(v0.z), w0, a2);
        a3 = fmaf(bf2f(v0.w), w0, a3);
    }
    if (dg > CAP && g == 0) {          // exact-overflow path (empty in practice)
        int sc = *spill_cnt;
        for (int i = 0; i < sc; ++i) {
            int2 sp = spill[i];
            if (sp.x == n) {
                int e = sp.y;
                int s0 = src[e];
                float w0 = wl[e];
                ushort4 v0 = yv[(size_t)s0 * TPN + lane];
                a0 = fmaf(bf2f(v0.x), w0, a0);
                a1 = fmaf(bf2f(v0.y), w0, a1);
                a2 = fmaf(bf2f(v0.z), w0, a2);
                a3 = fmaf(bf2f(v0.w), w0, a3);
            }
        }
    }

    // cross-group combine (lanes g>0 fold into g==0)
    #pragma unroll
    for (int m = TPN; m < 64; m <<= 1) {
        a0 += __shfl_xor(a0, m, 64);
        a1 += __shfl_xor(a1, m, 64);
        a2 += __shfl_xor(a2, m, 64);
        a3 += __shfl_xor(a3, m, 64);
    }
    if (g != 0) return;

    const float inv = invi[n];
    if (FINAL) {
        float* out = (float*)outp;
        const int c = lane * 4;
        float aa[4] = {a0, a1, a2, a3};
        #pragma unroll
        for (int j = 0; j < 4; ++j) {
            if (c + j < 47) out[(size_t)n * 47 + c + j] = fmaf(aa[j], inv, b[c + j]);
        }
    } else {
        unsigned short* out = (unsigned short*)outp;
        const float io = invo[n];
        float4 bb = *(const float4*)&b[lane * 4];
        float4 v;
        v.x = fmaxf(fmaf(a0, inv, bb.x), 0.f) * io;
        v.y = fmaxf(fmaf(a1, inv, bb.y), 0.f) * io;
        v.z = fmaxf(fmaf(a2, inv, bb.z), 0.f) * io;
        v.w = fmaxf(fmaf(a3, inv, bb.w), 0.f) * io;
        ushort4 o;
        o.x = f2bf(v.x); o.y = f2bf(v.y); o.z = f2bf(v.z); o.w = f2bf(v.w);
        *(ushort4*)&out[(size_t)n * PC + lane * 4] = o;
    }
}

extern "C" void kernel_launch(void* const* d_in, const int* in_sizes, int n_in,
                              void* d_out, int out_size, void* d_ws, size_t ws_size,
                              hipStream_t stream) {
    const float* x   = (const float*)d_in[0];
    const int*   src = (const int*)d_in[1];
    const int*   dst = (const int*)d_in[2];
    const float* w   = (const float*)d_in[3];
    const float* W0  = (const float*)d_in[4];
    const float* b0  = (const float*)d_in[5];
    const float* W1  = (const float*)d_in[6];
    const float* b1  = (const float*)d_in[7];
    const float* W2  = (const float*)d_in[8];
    const float* b2  = (const float*)d_in[9];

    const int N = in_sizes[0] / 128;
    const int E = in_sizes[1];

    char* p = (char*)d_ws;
    unsigned short* xh = (unsigned short*)p; p += (size_t)N * 128 * sizeof(unsigned short); // x_bf16 / hb (aliased)
    unsigned short* y  = (unsigned short*)p; p += (size_t)N * 128 * sizeof(unsigned short);
    float4* swb    = (float4*)p; p += (size_t)N * CAP * sizeof(float4);
    int2*   spill  = (int2*)p;   p += (size_t)E * sizeof(int2);
    unsigned short* Wp = (unsigned short*)p; p += (size_t)(16384 * 2 + 8192) * sizeof(unsigned short);
    int*   dego    = (int*)p;    p += (size_t)N * sizeof(int);
    int*   cursor  = (int*)p;    p += (size_t)N * sizeof(int);   // becomes degi
    int*   spill_cnt = (int*)p;  p += 4 * sizeof(int);
    float* invo    = (float*)p;  p += (size_t)N * sizeof(float);
    float* invi    = (float*)p;  p += (size_t)N * sizeof(float);

    unsigned short* Wp0 = Wp;
    unsigned short* Wp1 = Wp + 16384;
    unsigned short* Wp2 = Wp + 32768;

    // ---- weight packs ----
    pack_w<<<(128 * 128 + 255) / 256, 256, 0, stream>>>(W0, 128, 128, Wp0);
    pack_w<<<(128 * 128 + 255) / 256, 256, 0, stream>>>(W1, 128, 128, Wp1);
    pack_w<<<(128 * 64 + 255) / 256, 256, 0, stream>>>(W2, 47, 64, Wp2);

    // ---- one-pass bucket build (degrees + records + spill) ----
    hipMemsetAsync(dego, 0, (2 * (size_t)N + 4) * sizeof(int), stream);
    fill_bucket<<<(E + 255) / 256, 256, 0, stream>>>(
        src, dst, w, E, dego, cursor, swb, spill_cnt, spill);
    invsqrt_kernel<<<(N + 255) / 256, 256, 0, stream>>>(dego, cursor, invo, invi, N);

    // ---- layer-0 input prescale ----
    prescale<<<(N * 32 + 255) / 256, 256, 0, stream>>>(x, invo, xh, N);

    const int gemm_blocks   = (N + 63) / 64;
    const int gather_blocks = (N + 3) / 4;

    // ---- layer 0: xh -> xh (via y) ----
    gemm_direct<128><<<gemm_blocks, 256, 0, stream>>>(xh, Wp0, y, N);
    gather_w<128, 0, false><<<gather_blocks, 256, 0, stream>>>(
        y, swb, cursor, spill_cnt, spill, src, w, invi, invo, b0, xh, N);

    // ---- layer 1: xh -> xh ----
    gemm_direct<128><<<gemm_blocks, 256, 0, stream>>>(xh, Wp1, y, N);
    gather_w<128, 1, false><<<gather_blocks, 256, 0, stream>>>(
        y, swb, cursor, spill_cnt, spill, src, w + E, invi, invo, b1, xh, N);

    // ---- layer 2: xh -> d_out ----
    gemm_direct<64><<<gemm_blocks, 256, 0, stream>>>(xh, Wp2, y, N);
    gather_w<64, 2, true><<<gather_blocks, 256, 0, stream>>>(
        y, swb, cursor, spill_cnt, spill, src, w + 2 * (size_t)E, invi, invo, b2, d_out, N);
}

// Round 9
// 254.991 us; speedup vs baseline: 5.1963x; 1.1553x over previous
//
#include <hip/hip_runtime.h>

// ---------------------------------------------------------------------------
// 3-layer GCN (DGL GraphConv, norm='both') on N=100k nodes, E=800k edges.
// Round 9: invo folded into gather edge-weight ((h*invo)@W = (h@W)*invo[s]),
// so layer-0 GEMM is graph-independent -> fused mega-kernel interleaves
// fill_bucket blocks (latency-bound, ~98% stalled) with gemm0 blocks (MFMA).
// prescale + invsqrt kernels deleted (on-the-fly rsqrt from degree arrays).
// Per layer: y = bf16(h @ W) ; h' = bf16(relu(sum_e y[s]*invo[s]*w[e] *invi + b))
// ---------------------------------------------------------------------------

typedef short s16x8 __attribute__((ext_vector_type(8)));
typedef float f32x4 __attribute__((ext_vector_type(4)));

static constexpr int CAP = 24;   // bucket slots per node (P(deg>24)~1e-6)

__device__ __forceinline__ unsigned short f2bf(float f) {
    unsigned int u = __float_as_uint(f);
    u += 0x7FFFu + ((u >> 16) & 1u);   // round-to-nearest-even
    return (unsigned short)(u >> 16);
}
__device__ __forceinline__ float bf2f(unsigned short v) {
    return __uint_as_float((unsigned int)v << 16);
}

// ---- one kernel packs all three weight matrices into MFMA fragment order --
// Fragment mapping (same for A and B, cancels HW k-order):
//   k = kk*32 + (lane>>4)*8 + j ; col = ct*16 + (lane&15)
__global__ __launch_bounds__(256)
void pack_all(const float* __restrict__ W0, const float* __restrict__ W1,
              const float* __restrict__ W2, unsigned short* __restrict__ Wp) {
    int idx = blockIdx.x * 256 + threadIdx.x;
    if (idx < 32768) {                       // W0 / W1, PC=128, dact=128
        const float* W = (idx < 16384) ? W0 : W1;
        unsigned short* D = Wp + ((idx < 16384) ? 0 : 16384);
        int i = idx & 16383;
        int k = i >> 7, col = i & 127;
        float v = W[k * 128 + col];
        int kk = k >> 5, kr = k & 31;
        int lane = ((kr >> 3) << 4) | (col & 15);
        int ct = col >> 4, j = kr & 7;
        D[(((kk * 8) + ct) * 64 + lane) * 8 + j] = f2bf(v);
    } else if (idx < 40960) {                // W2, PC=64, dact=47
        int i = idx - 32768;
        int k = i >> 6, col = i & 63;
        float v = (col < 47) ? W2[k * 47 + col] : 0.0f;
        int kk = k >> 5, kr = k & 31;
        int lane = ((kr >> 3) << 4) | (col & 15);
        int ct = col >> 4, j = kr & 7;
        (Wp + 32768)[(((kk * 4) + ct) * 64 + lane) * 8 + j] = f2bf(v);
    }
}

// ---------------------------------------------------------------------------
// Mega-kernel: interleaved graph build + layer-0 GEMM.
// blockIdx % 3 == 2 -> gemm0 block (64 rows, x f32 -> bf16 frags -> MFMA);
// else              -> fill block (256 edges: 2 atomics + one float4 record).
// The fill blocks are ~98% memory-stalled; gemm0 runs in their idle cycles.
// ---------------------------------------------------------------------------
__global__ __launch_bounds__(256)
void mega_fill_gemm0(const int* __restrict__ src, const int* __restrict__ dst,
                     const float* __restrict__ w, int E,
                     int* __restrict__ dego, int* __restrict__ cursor,
                     float4* __restrict__ swb,
                     int* __restrict__ spill_cnt, int2* __restrict__ spill,
                     const float* __restrict__ x,
                     const unsigned short* __restrict__ Wp0,
                     unsigned short* __restrict__ y, int N, int gemm_blocks) {
    const int b = blockIdx.x;
    if (b % 3 == 2) {
        // ---- gemm0: y[N][128] = bf16( bf16(x) @ Wp0 ) ----
        const int gb = b / 3;
        if (gb >= gemm_blocks) return;
        const int lane = threadIdx.x & 63;
        const int wid  = threadIdx.x >> 6;
        const int row0 = gb * 64 + wid * 16;
        const int kgrp = lane >> 4;
        const int c    = lane & 15;
        int ar = row0 + c;
        if (ar > N - 1) ar = N - 1;
        const float* xrow = &x[(size_t)ar * 128];

        f32x4 acc[8];
        #pragma unroll
        for (int ct = 0; ct < 8; ++ct) acc[ct] = {0.f, 0.f, 0.f, 0.f};

        #pragma unroll
        for (int kk = 0; kk < 4; ++kk) {
            float4 u0 = *(const float4*)&xrow[kk * 32 + kgrp * 8];
            float4 u1 = *(const float4*)&xrow[kk * 32 + kgrp * 8 + 4];
            s16x8 af;
            af[0] = (short)f2bf(u0.x); af[1] = (short)f2bf(u0.y);
            af[2] = (short)f2bf(u0.z); af[3] = (short)f2bf(u0.w);
            af[4] = (short)f2bf(u1.x); af[5] = (short)f2bf(u1.y);
            af[6] = (short)f2bf(u1.z); af[7] = (short)f2bf(u1.w);
            #pragma unroll
            for (int ct = 0; ct < 8; ++ct) {
                s16x8 bf = *(const s16x8*)&Wp0[((size_t)(kk * 8 + ct) * 64 + lane) * 8];
                acc[ct] = __builtin_amdgcn_mfma_f32_16x16x32_bf16(af, bf, acc[ct], 0, 0, 0);
            }
        }
        #pragma unroll
        for (int ct = 0; ct < 8; ++ct) {
            #pragma unroll
            for (int i = 0; i < 4; ++i) {
                int row = row0 + kgrp * 4 + i;
                if (row < N) y[(size_t)row * 128 + ct * 16 + c] = f2bf(acc[ct][i]);
            }
        }
    } else {
        // ---- fill: one edge per thread ----
        const int fb = b - b / 3;            // sequential index over non-gemm blocks
        int e = fb * 256 + (int)threadIdx.x;
        if (e >= E) return;
        int s = src[e];
        int d = dst[e];
        atomicAdd(&dego[s], 1);
        int pos = atomicAdd(&cursor[d], 1);
        if (pos < CAP) {
            swb[(size_t)d * CAP + pos] =
                make_float4(__int_as_float(s), w[e], w[E + e], w[2 * (size_t)E + e]);
        } else {
            int sp = atomicAdd(spill_cnt, 1);
            spill[sp] = make_int2(d, e);
        }
    }
}

// ---------------------------------------------------------------------------
// LDS-free MFMA GEMM (layers 1,2): y[N][PC](bf16) = bf16( h[N][128](bf16) @ Wp )
// Block = 4 waves = 64 rows; wave computes 16 rows x PC cols; K=128 in 4 steps.
// C/D layout: col = ct*16 + (lane&15), row = (lane>>4)*4 + i.
// ---------------------------------------------------------------------------
template<int PC>
__global__ __launch_bounds__(256)
void gemm_direct(const unsigned short* __restrict__ h,
                 const unsigned short* __restrict__ Wp,
                 unsigned short* __restrict__ y, int N) {
    constexpr int CT = PC / 16;
    const int lane = threadIdx.x & 63;
    const int wid  = threadIdx.x >> 6;
    const int row0 = blockIdx.x * 64 + wid * 16;
    const int kgrp = lane >> 4;
    const int c    = lane & 15;

    int ar = row0 + c;
    if (ar > N - 1) ar = N - 1;
    const unsigned short* hrow = &h[(size_t)ar * 128 + kgrp * 8];

    f32x4 acc[CT];
    #pragma unroll
    for (int ct = 0; ct < CT; ++ct) acc[ct] = {0.f, 0.f, 0.f, 0.f};

    #pragma unroll
    for (int kk = 0; kk < 4; ++kk) {
        s16x8 af = *(const s16x8*)&hrow[kk * 32];
        #pragma unroll
        for (int ct = 0; ct < CT; ++ct) {
            s16x8 bf = *(const s16x8*)&Wp[((size_t)(kk * CT + ct) * 64 + lane) * 8];
            acc[ct] = __builtin_amdgcn_mfma_f32_16x16x32_bf16(af, bf, acc[ct], 0, 0, 0);
        }
    }

    #pragma unroll
    for (int ct = 0; ct < CT; ++ct) {
        #pragma unroll
        for (int i = 0; i < 4; ++i) {
            int row = row0 + kgrp * 4 + i;
            if (row < N) y[(size_t)row * PC + ct * 16 + c] = f2bf(acc[ct][i]);
        }
    }
}

// ---------------------------------------------------------------------------
// Wave-per-node gather + fused finalize, invo folded per edge.
// TPN = PC/4 lanes cover one row; EPG = 64/TPN edge groups take interleaved
// slots; 4/2/1-deep unrolled loads; shfl_xor cross-group combine.
// edge weight = w[e] * rsqrt(max(outdeg[src],1)); invi = rsqrt(max(indeg,1)).
// Non-final: out = bf16(relu(acc*invi + b)), pitch 128 bf16.
// Final:     out = acc*invi + b, f32, pitch 47, cols < 47 only.
// ---------------------------------------------------------------------------
template<int PC, int WSEL, bool FINAL>
__global__ __launch_bounds__(256)
void gather_w(const unsigned short* __restrict__ yb, const float4* __restrict__ swb,
              const int* __restrict__ degi, const int* __restrict__ dego,
              const int* __restrict__ spill_cnt, const int2* __restrict__ spill,
              const int* __restrict__ src, const float* __restrict__ wl,
              const float* __restrict__ b, void* __restrict__ outp, int N) {
    constexpr int TPN = PC / 4;
    constexpr int EPG = 64 / TPN;
    const int n = blockIdx.x * 4 + (threadIdx.x >> 6);
    if (n >= N) return;
    const int t    = threadIdx.x & 63;
    const int lane = t & (TPN - 1);
    const int g    = t / TPN;

    const ushort4* yv = (const ushort4*)yb;
    const float4* rec = swb + (size_t)n * CAP;
    const int dg  = degi[n];
    const int cnt = dg < CAP ? dg : CAP;

    float a0 = 0.f, a1 = 0.f, a2 = 0.f, a3 = 0.f;
    int p = g;

#define SELW(m) ((WSEL == 0) ? (m).y : (WSEL == 1) ? (m).z : (m).w)
#define EDGE_FMA(m, v) do {                                                   \
        int _s = __float_as_int((m).x);                                       \
        int _d = dego[_s]; if (_d < 1) _d = 1;                                \
        float _w = SELW(m) * rsqrtf((float)_d);                               \
        a0 = fmaf(bf2f((v).x), _w, a0);                                       \
        a1 = fmaf(bf2f((v).y), _w, a1);                                       \
        a2 = fmaf(bf2f((v).z), _w, a2);                                       \
        a3 = fmaf(bf2f((v).w), _w, a3);                                       \
    } while (0)

    for (; p + 3 * EPG < cnt; p += 4 * EPG) {
        float4 m0 = rec[p];
        float4 m1 = rec[p + EPG];
        float4 m2 = rec[p + 2 * EPG];
        float4 m3 = rec[p + 3 * EPG];
        ushort4 v0 = yv[(size_t)__float_as_int(m0.x) * TPN + lane];
        ushort4 v1 = yv[(size_t)__float_as_int(m1.x) * TPN + lane];
        ushort4 v2 = yv[(size_t)__float_as_int(m2.x) * TPN + lane];
        ushort4 v3 = yv[(size_t)__float_as_int(m3.x) * TPN + lane];
        EDGE_FMA(m0, v0); EDGE_FMA(m1, v1); EDGE_FMA(m2, v2); EDGE_FMA(m3, v3);
    }
    for (; p + EPG < cnt; p += 2 * EPG) {
        float4 m0 = rec[p];
        float4 m1 = rec[p + EPG];
        ushort4 v0 = yv[(size_t)__float_as_int(m0.x) * TPN + lane];
        ushort4 v1 = yv[(size_t)__float_as_int(m1.x) * TPN + lane];
        EDGE_FMA(m0, v0); EDGE_FMA(m1, v1);
    }
    if (p < cnt) {
        float4 m0 = rec[p];
        ushort4 v0 = yv[(size_t)__float_as_int(m0.x) * TPN + lane];
        EDGE_FMA(m0, v0);
    }
    if (dg > CAP && g == 0) {            // exact-overflow path (empty in practice)
        int sc = *spill_cnt;
        for (int i = 0; i < sc; ++i) {
            int2 sp = spill[i];
            if (sp.x == n) {
                int e = sp.y;
                int s0 = src[e];
                int d0 = dego[s0]; if (d0 < 1) d0 = 1;
                float w0 = wl[e] * rsqrtf((float)d0);
                ushort4 v0 = yv[(size_t)s0 * TPN + lane];
                a0 = fmaf(bf2f(v0.x), w0, a0);
                a1 = fmaf(bf2f(v0.y), w0, a1);
                a2 = fmaf(bf2f(v0.z), w0, a2);
                a3 = fmaf(bf2f(v0.w), w0, a3);
            }
        }
    }
#undef EDGE_FMA
#undef SELW

    #pragma unroll
    for (int m = TPN; m < 64; m <<= 1) {
        a0 += __shfl_xor(a0, m, 64);
        a1 += __shfl_xor(a1, m, 64);
        a2 += __shfl_xor(a2, m, 64);
        a3 += __shfl_xor(a3, m, 64);
    }
    if (g != 0) return;

    const float inv = rsqrtf((float)(dg < 1 ? 1 : dg));
    if (FINAL) {
        float* out = (float*)outp;
        const int c = lane * 4;
        float aa[4] = {a0, a1, a2, a3};
        #pragma unroll
        for (int j = 0; j < 4; ++j) {
            if (c + j < 47) out[(size_t)n * 47 + c + j] = fmaf(aa[j], inv, b[c + j]);
        }
    } else {
        unsigned short* out = (unsigned short*)outp;
        float4 bb = *(const float4*)&b[lane * 4];
        float4 v;
        v.x = fmaxf(fmaf(a0, inv, bb.x), 0.f);
        v.y = fmaxf(fmaf(a1, inv, bb.y), 0.f);
        v.z = fmaxf(fmaf(a2, inv, bb.z), 0.f);
        v.w = fmaxf(fmaf(a3, inv, bb.w), 0.f);
        ushort4 o;
        o.x = f2bf(v.x); o.y = f2bf(v.y); o.z = f2bf(v.z); o.w = f2bf(v.w);
        *(ushort4*)&out[(size_t)n * PC + lane * 4] = o;
    }
}

extern "C" void kernel_launch(void* const* d_in, const int* in_sizes, int n_in,
                              void* d_out, int out_size, void* d_ws, size_t ws_size,
                              hipStream_t stream) {
    const float* x   = (const float*)d_in[0];
    const int*   src = (const int*)d_in[1];
    const int*   dst = (const int*)d_in[2];
    const float* w   = (const float*)d_in[3];
    const float* W0  = (const float*)d_in[4];
    const float* b0  = (const float*)d_in[5];
    const float* W1  = (const float*)d_in[6];
    const float* b1  = (const float*)d_in[7];
    const float* W2  = (const float*)d_in[8];
    const float* b2  = (const float*)d_in[9];

    const int N = in_sizes[0] / 128;
    const int E = in_sizes[1];

    char* p = (char*)d_ws;
    unsigned short* xh = (unsigned short*)p; p += (size_t)N * 128 * sizeof(unsigned short); // hidden state
    unsigned short* y  = (unsigned short*)p; p += (size_t)N * 128 * sizeof(unsigned short);
    float4* swb    = (float4*)p; p += (size_t)N * CAP * sizeof(float4);
    int2*   spill  = (int2*)p;   p += (size_t)E * sizeof(int2);
    unsigned short* Wp = (unsigned short*)p; p += (size_t)(16384 * 2 + 8192) * sizeof(unsigned short);
    int*   dego    = (int*)p;    p += (size_t)N * sizeof(int);
    int*   cursor  = (int*)p;    p += (size_t)N * sizeof(int);   // becomes in-degree
    int*   spill_cnt = (int*)p;  p += 4 * sizeof(int);

    unsigned short* Wp1 = Wp + 16384;
    unsigned short* Wp2 = Wp + 32768;

    // ---- zero degree arrays + spill counter; pack all weights (1 kernel) ----
    hipMemsetAsync(dego, 0, (2 * (size_t)N + 4) * sizeof(int), stream);
    pack_all<<<160, 256, 0, stream>>>(W0, W1, W2, Wp);

    // ---- mega: graph build (fill) interleaved with layer-0 GEMM ----
    const int gemm_blocks = (N + 63) / 64;
    const int fill_blocks = (E + 255) / 256;
    int grid = 3 * gemm_blocks;
    if (grid - grid / 3 < fill_blocks) grid = (3 * fill_blocks + 1) / 2 + 2;
    mega_fill_gemm0<<<grid, 256, 0, stream>>>(
        src, dst, w, E, dego, cursor, swb, spill_cnt, spill,
        x, Wp, y, N, gemm_blocks);

    const int gather_blocks = (N + 3) / 4;

    // ---- layer 0 gather: y -> xh ----
    gather_w<128, 0, false><<<gather_blocks, 256, 0, stream>>>(
        y, swb, cursor, dego, spill_cnt, spill, src, w, b0, xh, N);

    // ---- layer 1 ----
    gemm_direct<128><<<gemm_blocks, 256, 0, stream>>>(xh, Wp1, y, N);
    gather_w<128, 1, false><<<gather_blocks, 256, 0, stream>>>(
        y, swb, cursor, dego, spill_cnt, spill, src, w + E, b1, xh, N);

    // ---- layer 2 ----
    gemm_direct<64><<<gemm_blocks, 256, 0, stream>>>(xh, Wp2, y, N);
    gather_w<64, 2, true><<<gather_blocks, 256, 0, stream>>>(
        y, swb, cursor, dego, spill_cnt, spill, src, w + 2 * (size_t)E, b2, d_out, N);
}